// Round 4
// baseline (307.723 us; speedup 1.0000x reference)
//
#include <hip/hip_runtime.h>

#define EPSV 1e-7f

typedef __bf16 bf16x8 __attribute__((ext_vector_type(8)));
typedef float  f32x4  __attribute__((ext_vector_type(4)));
typedef unsigned int   u32x4 __attribute__((ext_vector_type(4)));
typedef unsigned short u16x8 __attribute__((ext_vector_type(8)));
typedef unsigned short u16x4 __attribute__((ext_vector_type(4)));

__device__ __forceinline__ unsigned short f2bf(float f) {
    unsigned int u = __float_as_uint(f);
    return (unsigned short)((u + 0x7FFFu + ((u >> 16) & 1u)) >> 16);
}
__device__ __forceinline__ float bf2f(unsigned short u) {
    return __uint_as_float(((unsigned int)u) << 16);
}
__device__ __forceinline__ void split2(float f, unsigned short& hi, unsigned short& lo) {
    hi = f2bf(f);
    lo = f2bf(f - bf2f(hi));
}
__device__ __forceinline__ float sigf(float x) {
    return 1.0f / (1.0f + __expf(-x));
}
__device__ __forceinline__ float tanhfast(float x) {
    float cx = fminf(fmaxf(x, -15.0f), 15.0f);
    float e = __expf(2.0f * cx);
    return (e - 1.0f) / (e + 1.0f);
}

#define MFMA16(A, B, C) __builtin_amdgcn_mfma_f32_16x16x32_bf16(A, B, C, 0, 0, 0)
#define BC8(x) __builtin_bit_cast(bf16x8, x)

#define XS 200   // xh row stride: x_hi[0..63] h_hi[64..95] x_lo[96..159] h_lo[160..191]
#define MS 136   // mlps/hids: cat_hi[0..63] cat_lo[64..127]

// Block = 256 threads (4 waves) owns EIGHT batch rows (rows 8..15 of the MFMA
// tile are padding) -> grid 512 -> 2 blocks/CU -> 2 waves/SIMD for latency
// overlap. All GEMMs bf16 hi/lo split (fp32-grade). Gates in MFMA C/D register
// layout (lane^8 shuffle). Global loads prefetched one full step ahead.
__global__ __launch_bounds__(256) void tutina_kernel(
    const float* __restrict__ history, const float* __restrict__ control,
    const float* __restrict__ forecasts,
    const float* __restrict__ h_mean, const float* __restrict__ h_var,
    const float* __restrict__ c_mean, const float* __restrict__ c_var,
    const float* __restrict__ f_mean, const float* __restrict__ f_var,
    const float* __restrict__ conv_w, const float* __restrict__ conv_b,
    const float* __restrict__ lstm_k, const float* __restrict__ lstm_rk,
    const float* __restrict__ lstm_b,
    const float* __restrict__ w1, const float* __restrict__ b1,
    const float* __restrict__ w2, const float* __restrict__ b2,
    float* __restrict__ out)
{
    __shared__ unsigned short xh[2][16 * XS];   // ping-pong A staging
    __shared__ unsigned short mlps[16 * MS];
    __shared__ unsigned short hids[16 * MS];
    __shared__ float fcs[48 * 32];              // fc conv [t][b*4+u], b<8

    const int tid  = threadIdx.x;
    const int lane = tid & 63;
    const int wid  = tid >> 6;
    const int l15  = lane & 15;
    const int l4   = lane >> 4;
    const int b0   = blockIdx.x * 8;

    // ---- prologue: zero staging buffers (h=0 init, padding rows) ----
    for (int i = tid; i < 2 * 16 * XS; i += 256) ((unsigned short*)xh)[i] = 0;
    for (int i = tid; i < 16 * MS;     i += 256) mlps[i] = 0;

    // ---- gate-interleaved z-column assignment ----
    const int  uu     = l15 & 7;
    const bool lohalf = (l15 < 8);
    const int  u      = wid * 8 + uu;
    const int  jz0    = lohalf ? u      : 32 + u;
    const int  jz1    = lohalf ? 64 + u : 96 + u;
    const int  j1     = wid * 16 + l15;   // MLP/out column (0..63)

    auto bfrag2 = [&](const float* W, int ldw, int kbase, int j, int kmax,
                      bf16x8& H, bf16x8& L) {
        u16x8 h, l;
#pragma unroll
        for (int i = 0; i < 8; i++) {
            int k = kbase + l4 * 8 + i;
            float w = (k < kmax) ? W[k * ldw + j] : 0.0f;
            unsigned short hh, ll;
            split2(w, hh, ll);
            h[i] = hh; l[i] = ll;
        }
        H = BC8(h); L = BC8(l);
    };
    bf16x8 fA0h, fA0l, fA1h, fA1l, fA2h, fA2l;   // z0 (cols jz0)
    bf16x8 fB0h, fB0l, fB1h, fB1l, fB2h, fB2l;   // z1 (cols jz1)
    bf16x8 fW10h, fW10l, fW11h, fW11l, fW20h, fW20l, fW21h, fW21l;
    bfrag2(lstm_k, 128,  0, jz0, 64, fA0h, fA0l);
    bfrag2(lstm_k, 128, 32, jz0, 64, fA1h, fA1l);
    bfrag2(lstm_rk, 128, 0, jz0, 32, fA2h, fA2l);
    bfrag2(lstm_k, 128,  0, jz1, 64, fB0h, fB0l);
    bfrag2(lstm_k, 128, 32, jz1, 64, fB1h, fB1l);
    bfrag2(lstm_rk, 128, 0, jz1, 32, fB2h, fB2l);
    bfrag2(w1, 64,  0, j1, 52, fW10h, fW10l);
    bfrag2(w1, 64, 32, j1, 52, fW11h, fW11l);
    bfrag2(w2, 64,  0, j1, 64, fW20h, fW20l);
    bfrag2(w2, 64, 32, j1, 64, fW21h, fW21l);

    // per-lane constants
    float b1j = b1[j1], b2j = b2[j1];
    float hmj = h_mean[j1];
    float hsj = 1.0f / fmaxf(sqrtf(h_var[j1]), EPSV);
    float bi_ = lstm_b[u],      bf_ = lstm_b[32 + u];
    float bg_ = lstm_b[64 + u], bo_ = lstm_b[96 + u];

    // cell state: this lane owns unit u, rows r0, r0+1 (may be padding rows)
    const int r0 = l4 * 4 + (lohalf ? 0 : 2);
    const int r1 = r0 + 1;
    float c0 = 0.0f, c1 = 0.0f;

    // x-staging mapping: row rs (only rs<8 real), float4-group cs
    const int rs = tid >> 4;
    const int cs = tid & 15;
    float hm4[4], hs4[4];
#pragma unroll
    for (int q = 0; q < 4; q++) {
        hm4[q] = h_mean[cs * 4 + q];
        hs4[q] = 1.0f / fmaxf(sqrtf(h_var[cs * 4 + q]), EPSV);
    }
    const float* hrow = history + (size_t)(b0 + (rs < 8 ? rs : 0)) * (168 * 64) + cs * 4;

    // cn staging mapping (threads 0..31): rc in 0..7
    const int rc = tid >> 2, cc = (tid & 3) * 4;
    float cm4[4], cs4[4];
#pragma unroll
    for (int q = 0; q < 4; q++) {
        cm4[q] = c_mean[cc + q];
        cs4[q] = 1.0f / fmaxf(sqrtf(c_var[cc + q]), EPSV);
    }

    // ---- fc conv precompute: fc[t][b][u] fp32, b<8 ----
    {
        float fm  = f_mean[0];
        float fsc = 1.0f / fmaxf(sqrtf(f_var[0]), EPSV);
        for (int cell = tid; cell < 48 * 32; cell += 256) {
            int t  = cell >> 5;
            int b  = (cell >> 2) & 7;
            int uc = cell & 3;
            const float* fp = forecasts + ((size_t)(b0 + b) * 49 + t) * 8;
            float acc = conv_b[uc];
#pragma unroll
            for (int k = 0; k < 8; k++) {
                acc += (fp[k]     - fm) * fsc * conv_w[k * 4 + uc];
                acc += (fp[8 + k] - fm) * fsc * conv_w[32 + k * 4 + uc];
            }
            fcs[cell] = acc;
        }
    }

    auto stage_x = [&](unsigned short* dst, const f32x4& v) {
        if (rs < 8) {
            u16x4 oh, ol;
#pragma unroll
            for (int q = 0; q < 4; q++) {
                float n = (v[q] - hm4[q]) * hs4[q];
                unsigned short hh, ll;
                split2(n, hh, ll);
                oh[q] = hh; ol[q] = ll;
            }
            *(u16x4*)&dst[rs * XS + cs * 4]      = oh;
            *(u16x4*)&dst[rs * XS + 96 + cs * 4] = ol;
        }
    };

    auto lstm_mfma = [&](const unsigned short* src, f32x4& z0, f32x4& z1) {
        const int base = l15 * XS + l4 * 8;
        bf16x8 a0  = BC8(*(const u32x4*)&src[base]);
        bf16x8 a1  = BC8(*(const u32x4*)&src[base + 32]);
        bf16x8 a2  = BC8(*(const u32x4*)&src[base + 64]);
        bf16x8 a0l = BC8(*(const u32x4*)&src[base + 96]);
        bf16x8 a1l = BC8(*(const u32x4*)&src[base + 128]);
        bf16x8 a2l = BC8(*(const u32x4*)&src[base + 160]);
        z0 = f32x4{0.f, 0.f, 0.f, 0.f};
        z1 = f32x4{0.f, 0.f, 0.f, 0.f};
        z0 = MFMA16(a0,  fA0h, z0);  z1 = MFMA16(a0,  fB0h, z1);
        z0 = MFMA16(a1,  fA1h, z0);  z1 = MFMA16(a1,  fB1h, z1);
        z0 = MFMA16(a2,  fA2h, z0);  z1 = MFMA16(a2,  fB2h, z1);
        z0 = MFMA16(a0l, fA0h, z0);  z1 = MFMA16(a0l, fB0h, z1);
        z0 = MFMA16(a1l, fA1h, z0);  z1 = MFMA16(a1l, fB1h, z1);
        z0 = MFMA16(a2l, fA2h, z0);  z1 = MFMA16(a2l, fB2h, z1);
        z0 = MFMA16(a0,  fA0l, z0);  z1 = MFMA16(a0,  fB0l, z1);
        z0 = MFMA16(a1,  fA1l, z0);  z1 = MFMA16(a1,  fB1l, z1);
        z0 = MFMA16(a2,  fA2l, z0);  z1 = MFMA16(a2,  fB2l, z1);
    };

    auto lstm_gates = [&](const f32x4& a, const f32x4& b,
                          unsigned short* dst, bool write_mlp) {
        float sa0 = lohalf ? a[2] : a[0];
        float sa1 = lohalf ? a[3] : a[1];
        float sb0 = lohalf ? b[2] : b[0];
        float sb1 = lohalf ? b[3] : b[1];
        float ra0 = __shfl_xor(sa0, 8, 64);
        float ra1 = __shfl_xor(sa1, 8, 64);
        float rb0 = __shfl_xor(sb0, 8, 64);
        float rb1 = __shfl_xor(sb1, 8, 64);
        float zi0 = (lohalf ? a[0] : ra0) + bi_;
        float zi1 = (lohalf ? a[1] : ra1) + bi_;
        float zf0 = (lohalf ? ra0 : a[2]) + bf_;
        float zf1 = (lohalf ? ra1 : a[3]) + bf_;
        float zg0 = (lohalf ? b[0] : rb0) + bg_;
        float zg1 = (lohalf ? b[1] : rb1) + bg_;
        float zo0 = (lohalf ? rb0 : b[2]) + bo_;
        float zo1 = (lohalf ? rb1 : b[3]) + bo_;
        c0 = sigf(zf0) * c0 + sigf(zi0) * tanhfast(zg0);
        c1 = sigf(zf1) * c1 + sigf(zi1) * tanhfast(zg1);
        float h20 = sigf(zo0) * tanhfast(c0);
        float h21 = sigf(zo1) * tanhfast(c1);
        unsigned short bh, bl;
        split2(h20, bh, bl);
        dst[r0 * XS + 64 + u]  = bh;
        dst[r0 * XS + 160 + u] = bl;
        if (write_mlp) { mlps[r0 * MS + u] = bh; mlps[r0 * MS + 64 + u] = bl; }
        split2(h21, bh, bl);
        dst[r1 * XS + 64 + u]  = bh;
        dst[r1 * XS + 160 + u] = bl;
        if (write_mlp) { mlps[r1 * MS + u] = bh; mlps[r1 * MS + 64 + u] = bl; }
    };

    // ---- latest (rows 0..7 real; C/D layout col j1) — issue loads EARLY ----
    float lat0 = 0.f, lat1 = 0.f, lat2 = 0.f, lat3 = 0.f;
    if (l4 < 2) {
        lat0 = history[((size_t)(b0 + l4 * 4 + 0) * 168 + 167) * 64 + j1];
        lat1 = history[((size_t)(b0 + l4 * 4 + 1) * 168 + 167) * 64 + j1];
        lat2 = history[((size_t)(b0 + l4 * 4 + 2) * 168 + 167) * 64 + j1];
        lat3 = history[((size_t)(b0 + l4 * 4 + 3) * 168 + 167) * 64 + j1];
    }
    // control slice t=0 prefetch (threads 0..31)
    f32x4 creg = {0.f, 0.f, 0.f, 0.f};
    if (tid < 32)
        creg = *(const f32x4*)(control + ((size_t)(b0 + rc) * 48 + 0) * 16 + cc);

    // ---- x_0, x_1 prefetch ----
    f32x4 v0 = {0.f, 0.f, 0.f, 0.f}, vreg = {0.f, 0.f, 0.f, 0.f};
    if (rs < 8) {
        v0   = *(const f32x4*)(hrow);
        vreg = *(const f32x4*)(hrow + 64);
    }
    __syncthreads();                 // zeroing done
    stage_x(xh[0], v0);
    __syncthreads();                 // x_0 staged

    // ---- encoder: 168 steps, ONE barrier each, full-step prefetch ----
    for (int t = 0; t < 168; ++t) {
        const int cur = t & 1, nxt = cur ^ 1;
        stage_x(xh[nxt], vreg);                      // x_{t+1} from reg
        int tn2 = (t < 166) ? t + 2 : 167;
        if (rs < 8) vreg = *(const f32x4*)(hrow + (size_t)tn2 * 64);

        f32x4 z0, z1;
        lstm_mfma(xh[cur], z0, z1);
        lstm_gates(z0, z1, xh[nxt], t == 167);
        __syncthreads();
    }
    // h_168 in xh[0].h and mlps.h

    auto stage_cn = [&](const f32x4& v) {
        if (tid < 32) {
            u16x4 oh, ol;
#pragma unroll
            for (int q = 0; q < 4; q++) {
                float n = (v[q] - cm4[q]) * cs4[q];
                unsigned short hh, ll;
                split2(n, hh, ll);
                oh[q] = hh; ol[q] = ll;
            }
            *(u16x4*)&mlps[rc * MS + 32 + cc]      = oh;
            *(u16x4*)&mlps[rc * MS + 64 + 32 + cc] = ol;
        }
    };
    auto stage_fc = [&](int t) {
        if (tid >= 64 && tid < 96) {
            int q = tid - 64;  // 0..31
            unsigned short hh, ll;
            split2(fcs[t * 32 + q], hh, ll);
            mlps[(q >> 2) * MS + 48 + (q & 3)]      = hh;
            mlps[(q >> 2) * MS + 64 + 48 + (q & 3)] = ll;
        }
    };

    auto mlp1 = [&]() {
        const int mbase = l15 * MS + l4 * 8;
        bf16x8 m0  = BC8(*(const u32x4*)&mlps[mbase]);
        bf16x8 m1  = BC8(*(const u32x4*)&mlps[mbase + 32]);
        bf16x8 m0l = BC8(*(const u32x4*)&mlps[mbase + 64]);
        bf16x8 m1l = BC8(*(const u32x4*)&mlps[mbase + 96]);
        f32x4 hacc = {0.f, 0.f, 0.f, 0.f};
        hacc = MFMA16(m0,  fW10h, hacc);
        hacc = MFMA16(m1,  fW11h, hacc);
        hacc = MFMA16(m0l, fW10h, hacc);
        hacc = MFMA16(m1l, fW11h, hacc);
        hacc = MFMA16(m0,  fW10l, hacc);
        hacc = MFMA16(m1,  fW11l, hacc);
#pragma unroll
        for (int q = 0; q < 4; q++) {
            float hv = fmaxf(hacc[q] + b1j, 0.0f);
            unsigned short hh, ll;
            split2(hv, hh, ll);
            hids[(l4 * 4 + q) * MS + j1]      = hh;
            hids[(l4 * 4 + q) * MS + 64 + j1] = ll;
        }
    };
    auto mlp2 = [&]() {
        const int mbase = l15 * MS + l4 * 8;
        bf16x8 h0  = BC8(*(const u32x4*)&hids[mbase]);
        bf16x8 h1  = BC8(*(const u32x4*)&hids[mbase + 32]);
        bf16x8 h0l = BC8(*(const u32x4*)&hids[mbase + 64]);
        bf16x8 h1l = BC8(*(const u32x4*)&hids[mbase + 96]);
        f32x4 oacc = {0.f, 0.f, 0.f, 0.f};
        oacc = MFMA16(h0,  fW20h, oacc);
        oacc = MFMA16(h1,  fW21h, oacc);
        oacc = MFMA16(h0l, fW20h, oacc);
        oacc = MFMA16(h1l, fW21h, oacc);
        oacc = MFMA16(h0,  fW20l, oacc);
        oacc = MFMA16(h1,  fW21l, oacc);
        lat0 += oacc[0] + b2j;
        lat1 += oacc[1] + b2j;
        lat2 += oacc[2] + b2j;
        lat3 += oacc[3] + b2j;
    };

    // ---- post-encoder MLP: latest += mlp(h_enc, cn_0, fc_0) ----
    stage_cn(creg);
    stage_fc(0);
    __syncthreads();
    mlp1();
    __syncthreads();
    mlp2();
    // creg still holds cn slice 0 (reused by decoder iter 0)

    // ---- decoder: 48 steps ----
    for (int t = 0; t < 48; ++t) {
        const int p = t & 1;
        // phase 1: xn = norm(latest) -> xh[p].x ; cn/fc slice t -> mlps
        unsigned short bh, bl;
        split2((lat0 - hmj) * hsj, bh, bl);
        xh[p][(l4 * 4 + 0) * XS + j1] = bh; xh[p][(l4 * 4 + 0) * XS + 96 + j1] = bl;
        split2((lat1 - hmj) * hsj, bh, bl);
        xh[p][(l4 * 4 + 1) * XS + j1] = bh; xh[p][(l4 * 4 + 1) * XS + 96 + j1] = bl;
        split2((lat2 - hmj) * hsj, bh, bl);
        xh[p][(l4 * 4 + 2) * XS + j1] = bh; xh[p][(l4 * 4 + 2) * XS + 96 + j1] = bl;
        split2((lat3 - hmj) * hsj, bh, bl);
        xh[p][(l4 * 4 + 3) * XS + j1] = bh; xh[p][(l4 * 4 + 3) * XS + 96 + j1] = bl;
        stage_cn(creg);
        stage_fc(t);
        // prefetch control slice t+1 (full-iteration distance)
        int tn = (t < 47) ? t + 1 : 47;
        if (tid < 32)
            creg = *(const f32x4*)(control + ((size_t)(b0 + rc) * 48 + tn) * 16 + cc);
        __syncthreads();   // B1

        // phase 2: LSTM + in-reg gates; h2 -> xh[p^1].h + mlps.h
        f32x4 z0, z1;
        lstm_mfma(xh[p], z0, z1);
        lstm_gates(z0, z1, xh[p ^ 1], true);
        __syncthreads();   // B2

        // phase 3: MLP
        mlp1();
        __syncthreads();   // B3
        mlp2();

        if (l4 < 2) {
            out[((size_t)(b0 + l4 * 4 + 0) * 48 + t) * 64 + j1] = lat0;
            out[((size_t)(b0 + l4 * 4 + 1) * 48 + t) * 64 + j1] = lat1;
            out[((size_t)(b0 + l4 * 4 + 2) * 48 + t) * 64 + j1] = lat2;
            out[((size_t)(b0 + l4 * 4 + 3) * 48 + t) * 64 + j1] = lat3;
        }
    }
}

extern "C" void kernel_launch(void* const* d_in, const int* in_sizes, int n_in,
                              void* d_out, int out_size, void* d_ws, size_t ws_size,
                              hipStream_t stream) {
    tutina_kernel<<<dim3(512), dim3(256), 0, stream>>>(
        (const float*)d_in[0],  (const float*)d_in[1],  (const float*)d_in[2],
        (const float*)d_in[3],  (const float*)d_in[4],  (const float*)d_in[5],
        (const float*)d_in[6],  (const float*)d_in[7],  (const float*)d_in[8],
        (const float*)d_in[9],  (const float*)d_in[10], (const float*)d_in[11],
        (const float*)d_in[12], (const float*)d_in[13], (const float*)d_in[14],
        (const float*)d_in[15], (const float*)d_in[16], (const float*)d_in[17],
        (float*)d_out);
}

// Round 5
// 220.578 us; speedup vs baseline: 1.3951x; 1.3951x over previous
//
#include <hip/hip_runtime.h>

#define EPSV 1e-7f

typedef __bf16 bf16x8 __attribute__((ext_vector_type(8)));
typedef float  f32x4  __attribute__((ext_vector_type(4)));
typedef unsigned int   u32x4 __attribute__((ext_vector_type(4)));
typedef unsigned short u16x8 __attribute__((ext_vector_type(8)));
typedef unsigned short u16x4 __attribute__((ext_vector_type(4)));

__device__ __forceinline__ unsigned short f2bf(float f) {
    unsigned int u = __float_as_uint(f);
    return (unsigned short)((u + 0x7FFFu + ((u >> 16) & 1u)) >> 16);
}
__device__ __forceinline__ float bf2f(unsigned short u) {
    return __uint_as_float(((unsigned int)u) << 16);
}
__device__ __forceinline__ void split2(float f, unsigned short& hi, unsigned short& lo) {
    hi = f2bf(f);
    lo = f2bf(f - bf2f(hi));
}
__device__ __forceinline__ float sigf(float x) {
    return 1.0f / (1.0f + __expf(-x));
}
__device__ __forceinline__ float tanhfast(float x) {
    float cx = fminf(fmaxf(x, -15.0f), 15.0f);
    float e = __expf(2.0f * cx);
    return (e - 1.0f) / (e + 1.0f);
}
// lane^8 exchange via DPP row_ror:8 (within 16-lane rows) — replaces ds_bpermute
__device__ __forceinline__ float xor8(float v) {
    return __builtin_bit_cast(float, __builtin_amdgcn_update_dpp(
        0, __builtin_bit_cast(int, v), 0x128, 0xF, 0xF, true));
}

#define MFMA16(A, B, C) __builtin_amdgcn_mfma_f32_16x16x32_bf16(A, B, C, 0, 0, 0)
#define BC8(x) __builtin_bit_cast(bf16x8, x)

// Raw workgroup barrier: LDS-visibility only (lgkmcnt(0)), NO vmcnt drain ->
// global prefetch loads stay in flight across steps (unlike __syncthreads,
// which drains vmcnt(0) every barrier).
#define BARRIER() do {                                        \
    asm volatile("s_waitcnt lgkmcnt(0)" ::: "memory");        \
    __builtin_amdgcn_s_barrier();                             \
    __builtin_amdgcn_sched_barrier(0);                        \
} while (0)

#define XS 200   // xh row stride: x_hi[0..63] h_hi[64..95] x_lo[96..159] h_lo[160..191]
#define MS 136   // mlps/hids: cat_hi[0..63] cat_lo[64..127]

// Block = 256 threads (4 waves), 16 batch rows, full sequence. GEMMs: bf16
// hi/lo split (fp32-grade). Input norms folded into weights+biases. Gates in
// MFMA C/D register layout via DPP xor8. Raw barriers (no vmcnt drain).
__global__ __launch_bounds__(256) void tutina_kernel(
    const float* __restrict__ history, const float* __restrict__ control,
    const float* __restrict__ forecasts,
    const float* __restrict__ h_mean, const float* __restrict__ h_var,
    const float* __restrict__ c_mean, const float* __restrict__ c_var,
    const float* __restrict__ f_mean, const float* __restrict__ f_var,
    const float* __restrict__ conv_w, const float* __restrict__ conv_b,
    const float* __restrict__ lstm_k, const float* __restrict__ lstm_rk,
    const float* __restrict__ lstm_b,
    const float* __restrict__ w1, const float* __restrict__ b1,
    const float* __restrict__ w2, const float* __restrict__ b2,
    float* __restrict__ out)
{
    __shared__ unsigned short xh[2][16 * XS];   // ping-pong A staging
    __shared__ unsigned short mlps[16 * MS];
    __shared__ unsigned short hids[16 * MS];
    __shared__ float fcs[48 * 64];              // fc conv [t][b*4+u] fp32

    const int tid  = threadIdx.x;
    const int lane = tid & 63;
    const int wid  = tid >> 6;
    const int l15  = lane & 15;
    const int l4   = lane >> 4;
    const int b0   = blockIdx.x * 16;

    // ---- prologue: zero staging buffers (h=0 init, pad regions) ----
    for (int i = tid; i < 2 * 16 * XS; i += 256) ((unsigned short*)xh)[i] = 0;
    for (int i = tid; i < 16 * MS;     i += 256) mlps[i] = 0;

    // ---- gate-interleaved z-column assignment ----
    const int  uu     = l15 & 7;
    const bool lohalf = (l15 < 8);
    const int  u      = wid * 8 + uu;
    const int  jz0    = lohalf ? u      : 32 + u;
    const int  jz1    = lohalf ? 64 + u : 96 + u;
    const int  j1     = wid * 16 + l15;   // MLP/out column (0..63)

    // ---- weight fragments (hi/lo), x-norm folded into K; bias-fold dots ----
    auto bfragK = [&](int kbase, int j, float& dacc, bf16x8& H, bf16x8& L) {
        u16x8 h, l;
#pragma unroll
        for (int i = 0; i < 8; i++) {
            int k = kbase + l4 * 8 + i;
            float sv = 1.0f / fmaxf(sqrtf(h_var[k]), EPSV);
            float w  = lstm_k[k * 128 + j] * sv;
            dacc += h_mean[k] * w;
            unsigned short hh, ll; split2(w, hh, ll);
            h[i] = hh; l[i] = ll;
        }
        H = BC8(h); L = BC8(l);
    };
    auto bfragP = [&](const float* W, int ldw, int kbase, int j, bf16x8& H, bf16x8& L) {
        u16x8 h, l;
#pragma unroll
        for (int i = 0; i < 8; i++) {
            int k = kbase + l4 * 8 + i;
            float w = W[k * ldw + j];
            unsigned short hh, ll; split2(w, hh, ll);
            h[i] = hh; l[i] = ll;
        }
        H = BC8(h); L = BC8(l);
    };
    auto bfragW11 = [&](int j, float& dacc, bf16x8& H, bf16x8& L) {
        u16x8 h, l;
#pragma unroll
        for (int i = 0; i < 8; i++) {
            int k = 32 + l4 * 8 + i;   // 32..63
            float w = 0.0f;
            if (k < 52) {
                w = w1[k * 64 + j];
                if (k < 48) {
                    float sv = 1.0f / fmaxf(sqrtf(c_var[k - 32]), EPSV);
                    w *= sv;
                    dacc += c_mean[k - 32] * w;
                }
            }
            unsigned short hh, ll; split2(w, hh, ll);
            h[i] = hh; l[i] = ll;
        }
        H = BC8(h); L = BC8(l);
    };

    bf16x8 fA0h, fA0l, fA1h, fA1l, fA2h, fA2l;
    bf16x8 fB0h, fB0l, fB1h, fB1l, fB2h, fB2l;
    bf16x8 fW10h, fW10l, fW11h, fW11l, fW20h, fW20l, fW21h, fW21l;
    float dz0 = 0.f, dz1 = 0.f, d1 = 0.f;
    bfragK(0,  jz0, dz0, fA0h, fA0l);
    bfragK(32, jz0, dz0, fA1h, fA1l);
    bfragP(lstm_rk, 128, 0, jz0, fA2h, fA2l);
    bfragK(0,  jz1, dz1, fB0h, fB0l);
    bfragK(32, jz1, dz1, fB1h, fB1l);
    bfragP(lstm_rk, 128, 0, jz1, fB2h, fB2l);
    bfragP(w1, 64, 0, j1, fW10h, fW10l);
    bfragW11(j1, d1, fW11h, fW11l);
    bfragP(w2, 64, 0,  j1, fW20h, fW20l);
    bfragP(w2, 64, 32, j1, fW21h, fW21l);

    // reduce bias-fold dots across l4 groups (k is split over l4)
    dz0 += __shfl_xor(dz0, 16, 64); dz0 += __shfl_xor(dz0, 32, 64);
    dz1 += __shfl_xor(dz1, 16, 64); dz1 += __shfl_xor(dz1, 32, 64);
    d1  += __shfl_xor(d1, 16, 64);  d1  += __shfl_xor(d1, 32, 64);
    float pd0 = xor8(dz0), pd1 = xor8(dz1);
    const float bi_ = lstm_b[u]      - (lohalf ? dz0 : pd0);
    const float bf_ = lstm_b[32 + u] - (lohalf ? pd0 : dz0);
    const float bg_ = lstm_b[64 + u] - (lohalf ? dz1 : pd1);
    const float bo_ = lstm_b[96 + u] - (lohalf ? pd1 : dz1);
    const float b1j = b1[j1] - d1;
    const float b2j = b2[j1];

    // cell state: lane owns unit u, rows r0, r0+1
    const int r0 = l4 * 4 + (lohalf ? 0 : 2);
    const int r1 = r0 + 1;
    float c0 = 0.0f, c1 = 0.0f;

    // x-staging mapping: row rs, float4-group cs (raw values; norm folded)
    const int rs = tid >> 4;
    const int cs = tid & 15;
    const float* hrow = history + (size_t)(b0 + rs) * (168 * 64) + cs * 4;

    // cn staging mapping (threads 0..63)
    const int rc = tid >> 2, cc = (tid & 3) * 4;

    // ---- fc conv precompute: fc[t][b][u] fp32 ----
    {
        float fm  = f_mean[0];
        float fsc = 1.0f / fmaxf(sqrtf(f_var[0]), EPSV);
        for (int cell = tid; cell < 48 * 64; cell += 256) {
            int t  = cell >> 6;
            int b  = (cell >> 2) & 15;
            int uc = cell & 3;
            const float* fp = forecasts + ((size_t)(b0 + b) * 49 + t) * 8;
            float acc = conv_b[uc];
#pragma unroll
            for (int k = 0; k < 8; k++) {
                acc += (fp[k]     - fm) * fsc * conv_w[k * 4 + uc];
                acc += (fp[8 + k] - fm) * fsc * conv_w[32 + k * 4 + uc];
            }
            fcs[cell] = acc;
        }
    }

    auto stage_x = [&](unsigned short* dst, const f32x4& v) {
        u16x4 oh, ol;
#pragma unroll
        for (int q = 0; q < 4; q++) {
            unsigned short hh, ll;
            split2(v[q], hh, ll);
            oh[q] = hh; ol[q] = ll;
        }
        *(u16x4*)&dst[rs * XS + cs * 4]      = oh;
        *(u16x4*)&dst[rs * XS + 96 + cs * 4] = ol;
    };

    // ---- LSTM z GEMM: 18 MFMAs as 4 chains (depth 5) ----
    auto lstm_mfma = [&](const unsigned short* src, f32x4& z0, f32x4& z1) {
        const int base = l15 * XS + l4 * 8;
        bf16x8 a0  = BC8(*(const u32x4*)&src[base]);
        bf16x8 a1  = BC8(*(const u32x4*)&src[base + 32]);
        bf16x8 a2  = BC8(*(const u32x4*)&src[base + 64]);
        bf16x8 a0l = BC8(*(const u32x4*)&src[base + 96]);
        bf16x8 a1l = BC8(*(const u32x4*)&src[base + 128]);
        bf16x8 a2l = BC8(*(const u32x4*)&src[base + 160]);
        f32x4 z0a = {0.f,0.f,0.f,0.f}, z0b = {0.f,0.f,0.f,0.f};
        f32x4 z1a = {0.f,0.f,0.f,0.f}, z1b = {0.f,0.f,0.f,0.f};
        z0a = MFMA16(a0,  fA0h, z0a);  z1a = MFMA16(a0,  fB0h, z1a);
        z0b = MFMA16(a1,  fA1h, z0b);  z1b = MFMA16(a1,  fB1h, z1b);
        z0a = MFMA16(a2,  fA2h, z0a);  z1a = MFMA16(a2,  fB2h, z1a);
        z0b = MFMA16(a0l, fA0h, z0b);  z1b = MFMA16(a0l, fB0h, z1b);
        z0a = MFMA16(a1l, fA1h, z0a);  z1a = MFMA16(a1l, fB1h, z1a);
        z0b = MFMA16(a2l, fA2h, z0b);  z1b = MFMA16(a2l, fB2h, z1b);
        z0a = MFMA16(a0,  fA0l, z0a);  z1a = MFMA16(a0,  fB0l, z1a);
        z0b = MFMA16(a1,  fA1l, z0b);  z1b = MFMA16(a1,  fB1l, z1b);
        z0a = MFMA16(a2,  fA2l, z0a);  z1a = MFMA16(a2,  fB2l, z1a);
        z0 = z0a + z0b;
        z1 = z1a + z1b;
    };

    // ---- gates in C/D layout: DPP xor8 exchange, update c, write h2 ----
    auto lstm_gates = [&](const f32x4& a, const f32x4& b,
                          unsigned short* dst, bool write_mlp) {
        float sa0 = lohalf ? a[2] : a[0];
        float sa1 = lohalf ? a[3] : a[1];
        float sb0 = lohalf ? b[2] : b[0];
        float sb1 = lohalf ? b[3] : b[1];
        float ra0 = xor8(sa0);
        float ra1 = xor8(sa1);
        float rb0 = xor8(sb0);
        float rb1 = xor8(sb1);
        float zi0 = (lohalf ? a[0] : ra0) + bi_;
        float zi1 = (lohalf ? a[1] : ra1) + bi_;
        float zf0 = (lohalf ? ra0 : a[2]) + bf_;
        float zf1 = (lohalf ? ra1 : a[3]) + bf_;
        float zg0 = (lohalf ? b[0] : rb0) + bg_;
        float zg1 = (lohalf ? b[1] : rb1) + bg_;
        float zo0 = (lohalf ? rb0 : b[2]) + bo_;
        float zo1 = (lohalf ? rb1 : b[3]) + bo_;
        c0 = sigf(zf0) * c0 + sigf(zi0) * tanhfast(zg0);
        c1 = sigf(zf1) * c1 + sigf(zi1) * tanhfast(zg1);
        float h20 = sigf(zo0) * tanhfast(c0);
        float h21 = sigf(zo1) * tanhfast(c1);
        unsigned short bh, bl;
        split2(h20, bh, bl);
        dst[r0 * XS + 64 + u]  = bh;
        dst[r0 * XS + 160 + u] = bl;
        if (write_mlp) { mlps[r0 * MS + u] = bh; mlps[r0 * MS + 64 + u] = bl; }
        split2(h21, bh, bl);
        dst[r1 * XS + 64 + u]  = bh;
        dst[r1 * XS + 160 + u] = bl;
        if (write_mlp) { mlps[r1 * MS + u] = bh; mlps[r1 * MS + 64 + u] = bl; }
    };

    // ---- early loads: latest, control slice 0, x_0/x_1 ----
    float lat0 = history[((size_t)(b0 + l4 * 4 + 0) * 168 + 167) * 64 + j1];
    float lat1 = history[((size_t)(b0 + l4 * 4 + 1) * 168 + 167) * 64 + j1];
    float lat2 = history[((size_t)(b0 + l4 * 4 + 2) * 168 + 167) * 64 + j1];
    float lat3 = history[((size_t)(b0 + l4 * 4 + 3) * 168 + 167) * 64 + j1];
    f32x4 creg = {0.f, 0.f, 0.f, 0.f};
    if (tid < 64)
        creg = *(const f32x4*)(control + ((size_t)(b0 + rc) * 48 + 0) * 16 + cc);
    f32x4 v0   = *(const f32x4*)(hrow);
    f32x4 vreg = *(const f32x4*)(hrow + 64);

    BARRIER();                 // zeroing visible
    stage_x(xh[0], v0);
    BARRIER();                 // x_0 staged

    // ---- encoder: 168 steps, ONE raw barrier each; prefetch floats across ----
    for (int t = 0; t < 168; ++t) {
        const int cur = t & 1, nxt = cur ^ 1;
        stage_x(xh[nxt], vreg);                      // x_{t+1} from reg
        int tn2 = (t < 166) ? t + 2 : 167;
        vreg = *(const f32x4*)(hrow + (size_t)tn2 * 64);   // in flight ~1 step

        f32x4 z0, z1;
        lstm_mfma(xh[cur], z0, z1);
        lstm_gates(z0, z1, xh[nxt], t == 167);
        BARRIER();
    }
    // h_168 in xh[0].h and mlps.h

    auto stage_cn = [&](const f32x4& v) {
        if (tid < 64) {
            u16x4 oh, ol;
#pragma unroll
            for (int q = 0; q < 4; q++) {
                unsigned short hh, ll;
                split2(v[q], hh, ll);
                oh[q] = hh; ol[q] = ll;
            }
            *(u16x4*)&mlps[rc * MS + 32 + cc]      = oh;
            *(u16x4*)&mlps[rc * MS + 64 + 32 + cc] = ol;
        }
    };
    auto stage_fc = [&](int t) {
        if (tid >= 64 && tid < 128) {
            int q = tid - 64;   // 0..63
            unsigned short hh, ll;
            split2(fcs[t * 64 + q], hh, ll);
            mlps[(q >> 2) * MS + 48 + (q & 3)]      = hh;
            mlps[(q >> 2) * MS + 64 + 48 + (q & 3)] = ll;
        }
    };

    auto mlp1 = [&]() {
        const int mbase = l15 * MS + l4 * 8;
        bf16x8 m0  = BC8(*(const u32x4*)&mlps[mbase]);
        bf16x8 m1  = BC8(*(const u32x4*)&mlps[mbase + 32]);
        bf16x8 m0l = BC8(*(const u32x4*)&mlps[mbase + 64]);
        bf16x8 m1l = BC8(*(const u32x4*)&mlps[mbase + 96]);
        f32x4 ha = {0.f,0.f,0.f,0.f}, hb = {0.f,0.f,0.f,0.f};
        ha = MFMA16(m0,  fW10h, ha);   hb = MFMA16(m1,  fW11h, hb);
        ha = MFMA16(m0l, fW10h, ha);   hb = MFMA16(m1l, fW11h, hb);
        ha = MFMA16(m0,  fW10l, ha);   hb = MFMA16(m1,  fW11l, hb);
        f32x4 hacc = ha + hb;
#pragma unroll
        for (int q = 0; q < 4; q++) {
            float hv = fmaxf(hacc[q] + b1j, 0.0f);
            unsigned short hh, ll;
            split2(hv, hh, ll);
            hids[(l4 * 4 + q) * MS + j1]      = hh;
            hids[(l4 * 4 + q) * MS + 64 + j1] = ll;
        }
    };
    auto mlp2 = [&]() {
        const int mbase = l15 * MS + l4 * 8;
        bf16x8 h0  = BC8(*(const u32x4*)&hids[mbase]);
        bf16x8 h1  = BC8(*(const u32x4*)&hids[mbase + 32]);
        bf16x8 h0l = BC8(*(const u32x4*)&hids[mbase + 64]);
        bf16x8 h1l = BC8(*(const u32x4*)&hids[mbase + 96]);
        f32x4 oa = {0.f,0.f,0.f,0.f}, ob = {0.f,0.f,0.f,0.f};
        oa = MFMA16(h0,  fW20h, oa);   ob = MFMA16(h1,  fW21h, ob);
        oa = MFMA16(h0l, fW20h, oa);   ob = MFMA16(h1l, fW21h, ob);
        oa = MFMA16(h0,  fW20l, oa);   ob = MFMA16(h1,  fW21l, ob);
        f32x4 oacc = oa + ob;
        lat0 += oacc[0] + b2j;
        lat1 += oacc[1] + b2j;
        lat2 += oacc[2] + b2j;
        lat3 += oacc[3] + b2j;
    };

    // ---- post-encoder MLP: latest += mlp(h_enc, cn_0, fc_0) ----
    stage_cn(creg);
    stage_fc(0);
    BARRIER();
    mlp1();
    BARRIER();
    mlp2();
    // creg still holds cn slice 0 (decoder iter 0 restages it)

    // ---- decoder: 48 steps, 3 raw barriers each ----
    for (int t = 0; t < 48; ++t) {
        const int p = t & 1;
        // phase 1: xn staged raw (norm folded into K); cn/fc slice t
        unsigned short bh, bl;
        split2(lat0, bh, bl);
        xh[p][(l4 * 4 + 0) * XS + j1] = bh; xh[p][(l4 * 4 + 0) * XS + 96 + j1] = bl;
        split2(lat1, bh, bl);
        xh[p][(l4 * 4 + 1) * XS + j1] = bh; xh[p][(l4 * 4 + 1) * XS + 96 + j1] = bl;
        split2(lat2, bh, bl);
        xh[p][(l4 * 4 + 2) * XS + j1] = bh; xh[p][(l4 * 4 + 2) * XS + 96 + j1] = bl;
        split2(lat3, bh, bl);
        xh[p][(l4 * 4 + 3) * XS + j1] = bh; xh[p][(l4 * 4 + 3) * XS + 96 + j1] = bl;
        stage_cn(creg);
        stage_fc(t);
        int tn = (t < 47) ? t + 1 : 47;
        if (tid < 64)
            creg = *(const f32x4*)(control + ((size_t)(b0 + rc) * 48 + tn) * 16 + cc);
        BARRIER();   // B1

        // phase 2: LSTM + in-reg gates; h2 -> xh[p^1].h + mlps.h
        f32x4 z0, z1;
        lstm_mfma(xh[p], z0, z1);
        lstm_gates(z0, z1, xh[p ^ 1], true);
        BARRIER();   // B2

        // phase 3: MLP
        mlp1();
        BARRIER();   // B3
        mlp2();

        out[((size_t)(b0 + l4 * 4 + 0) * 48 + t) * 64 + j1] = lat0;
        out[((size_t)(b0 + l4 * 4 + 1) * 48 + t) * 64 + j1] = lat1;
        out[((size_t)(b0 + l4 * 4 + 2) * 48 + t) * 64 + j1] = lat2;
        out[((size_t)(b0 + l4 * 4 + 3) * 48 + t) * 64 + j1] = lat3;
    }
}

extern "C" void kernel_launch(void* const* d_in, const int* in_sizes, int n_in,
                              void* d_out, int out_size, void* d_ws, size_t ws_size,
                              hipStream_t stream) {
    tutina_kernel<<<dim3(256), dim3(256), 0, stream>>>(
        (const float*)d_in[0],  (const float*)d_in[1],  (const float*)d_in[2],
        (const float*)d_in[3],  (const float*)d_in[4],  (const float*)d_in[5],
        (const float*)d_in[6],  (const float*)d_in[7],  (const float*)d_in[8],
        (const float*)d_in[9],  (const float*)d_in[10], (const float*)d_in[11],
        (const float*)d_in[12], (const float*)d_in[13], (const float*)d_in[14],
        (const float*)d_in[15], (const float*)d_in[16], (const float*)d_in[17],
        (float*)d_out);
}